// Round 6
// baseline (1199.826 us; speedup 1.0000x reference)
//
#include <hip/hip_runtime.h>
#include <cstdint>

#define BH    64
#define NSEQ  4096
#define DH    64
#define MF    256
#define EPS   1e-6f

typedef float f32;
typedef __attribute__((ext_vector_type(4))) float f32x4;

// ws layout: [ctx: 64*256*64 f32][ksum: 64*256 f32]
#define CTX_FLOATS (BH * MF * 64)
#define WS_FLOATS  (CTX_FLOATS + BH * MF)   // 1,064,960 floats = 266,240 quads
#define ZV ((f32x4){0.f, 0.f, 0.f, 0.f})
#define SW(q, r) ((q) ^ ((r) & 15))

// gelu(s) = 0.5*s*(1+erf(s/sqrt2)) + EPS, erf via A&S 7.1.26 (|err|<=1.5e-7)
__device__ __forceinline__ float gelu_eps(float s) {
    float x  = s * 0.70710678118654752f;
    float ax = fabsf(x);
    float t  = __builtin_amdgcn_rcpf(fmaf(0.3275911f, ax, 1.0f));
    float p  = t * fmaf(t, fmaf(t, fmaf(t, fmaf(t, 1.061405429f, -1.453152027f),
                                        1.421413741f), -0.284496736f), 0.254829592f);
    float e  = __expf(-(ax * ax));
    float er = copysignf(fmaf(-p, e, 1.0f), x);
    return fmaf(0.5f * s, er, fmaf(0.5f, s, EPS));
}

__global__ void zero_ws_kernel(f32x4* __restrict__ p) {
    p[blockIdx.x * 256 + threadIdx.x] = ZV;
}

// stage P^T chunk f (64 feats x 64 d) transposed+swizzled: sP[d][fq ^ (d&15)]
__device__ __forceinline__ void stage_P(const f32* __restrict__ Pg_, int f,
                                        f32x4* sP, int tid) {
    const f32x4* Pg = (const f32x4*)(Pg_ + (size_t)f * 64 * DH);
    f32* base = (f32*)sP;
    #pragma unroll
    for (int p = 0; p < 4; ++p) {
        int m2 = tid + p * 256;          // 0..1023
        int feat = m2 >> 4, dq = m2 & 15;
        f32x4 val = Pg[m2];
        #pragma unroll
        for (int jj = 0; jj < 4; ++jj) {
            int d = dq * 4 + jj;
            base[d * 64 + (SW(feat >> 2, d) << 2) + (feat & 3)] = val[jj];
        }
    }
}

// ---------------------------------------------------------------------------
// kside: grid 64bh x 4rg x 4f, 1024 blocks (= 4/CU residency; round-0's grid
// of 512 was the occupancy cap: 2 blocks/CU, 18% occ, latency-bound).
// Block: 1024 rows as 16 tiles x 64. kp = gelu(K@P^T)+eps ; ctx += kp^T@V ;
// ksum += colsum(kp). LDS 32 KB (sP 16 + kp 16) -> 5 blocks by LDS;
// launch_bounds(256,4) pins <=128 VGPR -> 4 blocks/CU.
// ---------------------------------------------------------------------------
__global__ __launch_bounds__(256, 4) void kside_kernel(
    const f32* __restrict__ Kg_, const f32* __restrict__ Vg_,
    const f32* __restrict__ Pg_, f32* __restrict__ ctx_ws,
    f32* __restrict__ ksum_ws)
{
    __shared__ f32x4 sP[64 * 16];    // 16 KB
    __shared__ f32x4 kp[64 * 16];    // 16 KB, [row][q ^ (row&15)]

    const int tid = threadIdx.x;
    // XCD swizzle (proven: FETCH 264->66 MB): same-bh blocks share K/V rows;
    // slot = j*64 + bh => slot%8 = bh%8 -> one XCD's L2.  b = bh*16 + j.
    const int b   = ((blockIdx.x & 63) << 4) | (blockIdx.x >> 6);
    const int f   = b & 3;
    const int rg4 = (b >> 2) & 3;
    const int bh  = b >> 4;
    const size_t rowbase = (size_t)bh * NSEQ + (size_t)rg4 * 1024;

    const int srg = tid >> 4, sfg = tid & 15;   // S: 16 grp x 4 rows, 16 fq
    const int g  = tid >> 7, t7 = tid & 127;    // ctx: 2 grp x 32 k
    const int cfg = t7 >> 3, ceg = t7 & 7;      // 16 fq x 8 e-pairs

    stage_P(Pg_, f, sP, tid);
    __syncthreads();

    f32x4 ctxacc[4][2];              // 4 feats (quad cfg) x 8 e = 32 floats
    f32x4 ksp = ZV;
    #pragma unroll
    for (int fi = 0; fi < 4; ++fi) { ctxacc[fi][0] = ZV; ctxacc[fi][1] = ZV; }

    for (int t = 0; t < 16; ++t) {
        const f32* Kg = Kg_ + (rowbase + t * 64) * DH;

        // S-GEMM: 4 rows x 4 feats, K=64
        f32x4 s[4];
        #pragma unroll
        for (int j = 0; j < 4; ++j) s[j] = ZV;
        #pragma unroll 4
        for (int kb = 0; kb < 16; ++kb) {
            f32x4 a[4];
            #pragma unroll
            for (int j = 0; j < 4; ++j)
                a[j] = *(const f32x4*)(Kg + (size_t)(srg * 4 + j) * DH + kb * 4);
            #pragma unroll
            for (int kk = 0; kk < 4; ++kk) {
                int d = kb * 4 + kk;
                f32x4 bq = sP[d * 16 + SW(sfg, d)];
                #pragma unroll
                for (int j = 0; j < 4; ++j) s[j] += a[j][kk] * bq;
            }
        }
        f32x4 gq[4];
        #pragma unroll
        for (int j = 0; j < 4; ++j) {
            #pragma unroll
            for (int i = 0; i < 4; ++i) gq[j][i] = gelu_eps(s[j][i]);
            ksp += gq[j];
        }
        __syncthreads();   // prev-tile ctx-GEMM kp reads done
        #pragma unroll
        for (int j = 0; j < 4; ++j) {
            int row = srg * 4 + j;
            kp[row * 16 + SW(sfg, row)] = gq[j];
        }
        __syncthreads();   // kp ready

        // ctx-GEMM: group g covers rows g*32..+31; thread 4f x 8e
        const f32* Vg = Vg_ + (rowbase + t * 64 + g * 32) * DH;
        #pragma unroll 4
        for (int k = 0; k < 32; ++k) {
            int row = g * 32 + k;
            f32x4 a0 = kp[row * 16 + SW(cfg, row)];
            f32x4 b0 = *(const f32x4*)(Vg + (size_t)k * DH + ceg * 8);
            f32x4 b1 = *(const f32x4*)(Vg + (size_t)k * DH + ceg * 8 + 4);
            #pragma unroll
            for (int fi = 0; fi < 4; ++fi) {
                ctxacc[fi][0] += a0[fi] * b0;
                ctxacc[fi][1] += a0[fi] * b1;
            }
        }
    }

    // ksum: reduce 16 srg-partials via kp scratch (kp dead after barrier)
    __syncthreads();
    ((f32x4*)kp)[sfg * 16 + srg] = ksp;
    __syncthreads();
    if (tid < 16) {
        f32x4 sum = ZV;
        #pragma unroll
        for (int r = 0; r < 16; ++r) sum += ((f32x4*)kp)[tid * 16 + r];
        f32* kb_ = ksum_ws + (size_t)bh * MF + f * 64 + tid * 4;
        #pragma unroll
        for (int i = 0; i < 4; ++i) atomicAdd(kb_ + i, sum[i]);
    }

    // ctx writeback: total atomic count = 1024 blk x 256 thr x 32 = 8.4M,
    // identical to round-0 baseline (WRITE_SIZE ~262 MB = atomic RMW traffic)
    f32* cb = ctx_ws + ((size_t)bh * MF + f * 64 + cfg * 4) * 64 + ceg * 8;
    #pragma unroll
    for (int fi = 0; fi < 4; ++fi)
        #pragma unroll
        for (int h = 0; h < 2; ++h)
            #pragma unroll
            for (int ei = 0; ei < 4; ++ei)
                atomicAdd(cb + (size_t)fi * 64 + h * 4 + ei, ctxacc[fi][h][ei]);
}

// ---------------------------------------------------------------------------
// qside: grid 64bh x 64ch, 4096 blocks (was 2048; 64-row blocks -> LDS 33.8 KB
// -> 4 blocks/CU vs round-0's 3). qp = gelu(Q@P^T)+eps ; num = qp@ctx ;
// den = qp.ksum ; out = num/den. sP/sctx share sU (16 KB).
// ---------------------------------------------------------------------------
__global__ __launch_bounds__(256, 4) void qside_kernel(
    const f32* __restrict__ Qg_, const f32* __restrict__ Pg_,
    const f32* __restrict__ ctx_ws, const f32* __restrict__ ksum_ws,
    f32* __restrict__ out)
{
    __shared__ f32x4 qp[64 * 16];    // 16 KB
    __shared__ f32x4 sU[64 * 16];    // 16 KB: P^T then ctx chunk
    __shared__ f32x4 sks[64];        // 1 KB

    const int tid = threadIdx.x;
    // slot = j*64 + bh => same-bh -> same XCD (ctx/ksum L2 reuse)
    const int b   = ((blockIdx.x & 63) << 6) | (blockIdx.x >> 6);
    const int bh  = b >> 6;
    const int ch  = b & 63;
    const size_t rowbase = (size_t)bh * NSEQ + (size_t)ch * 64;

    const int rg = tid >> 4, cg = tid & 15;   // 16 grp x 4 rows ; 16 fq/eq

    if (tid < 64) sks[tid] = ((const f32x4*)(ksum_ws + (size_t)bh * MF))[tid];

    const f32* Qg = Qg_ + rowbase * DH;

    f32x4 num[4];
    float den[4];
    #pragma unroll
    for (int j = 0; j < 4; ++j) { num[j] = ZV; den[j] = 0.f; }

    for (int f = 0; f < 4; ++f) {
        stage_P(Pg_, f, sU, tid);
        __syncthreads();   // B1: sP ready (f=0 also covers sks)

        // S-GEMM: 4 rows x 4 feats, K=64
        f32x4 s[4];
        #pragma unroll
        for (int j = 0; j < 4; ++j) s[j] = ZV;
        #pragma unroll 4
        for (int kb = 0; kb < 16; ++kb) {
            f32x4 a[4];
            #pragma unroll
            for (int j = 0; j < 4; ++j)
                a[j] = *(const f32x4*)(Qg + (size_t)(rg * 4 + j) * DH + kb * 4);
            #pragma unroll
            for (int kk = 0; kk < 4; ++kk) {
                int d = kb * 4 + kk;
                f32x4 bq = sU[d * 16 + SW(cg, d)];
                #pragma unroll
                for (int j = 0; j < 4; ++j) s[j] += a[j][kk] * bq;
            }
        }
        #pragma unroll
        for (int j = 0; j < 4; ++j) {
            int row = rg * 4 + j;
            f32x4 gq;
            #pragma unroll
            for (int i = 0; i < 4; ++i) gq[i] = gelu_eps(s[j][i]);
            qp[row * 16 + SW(cg, row)] = gq;
        }
        __syncthreads();   // B2: qp ready AND sU (P) reads done

        {   // stage ctx chunk into sU, swizzled [k][eq ^ (k&15)]
            const f32x4* Cg = (const f32x4*)(ctx_ws + ((size_t)bh * MF + f * 64) * 64);
            #pragma unroll
            for (int p = 0; p < 4; ++p) {
                int m2 = tid + p * 256;
                int k = m2 >> 4, eq = m2 & 15;
                sU[k * 16 + SW(eq, k)] = Cg[m2];
            }
        }
        __syncthreads();   // B3: sctx ready

        // num-GEMM: 4 rows x 4 e, K=64 ; den folded in
        #pragma unroll 4
        for (int kb = 0; kb < 16; ++kb) {
            f32x4 a[4];
            #pragma unroll
            for (int j = 0; j < 4; ++j) {
                int row = rg * 4 + j;
                a[j] = qp[row * 16 + SW(kb, row)];
            }
            f32x4 ks = sks[f * 16 + kb];
            #pragma unroll
            for (int kk = 0; kk < 4; ++kk) {
                int k = kb * 4 + kk;
                f32x4 bq = sU[k * 16 + SW(cg, k)];
                #pragma unroll
                for (int j = 0; j < 4; ++j) num[j] += a[j][kk] * bq;
            }
            #pragma unroll
            for (int j = 0; j < 4; ++j)
                den[j] += a[j][0] * ks[0] + a[j][1] * ks[1]
                        + a[j][2] * ks[2] + a[j][3] * ks[3];
        }
        __syncthreads();   // B4: sU/qp reads done before next-f staging
    }

    #pragma unroll
    for (int j = 0; j < 4; ++j) {
        float dinv = 1.0f / den[j];
        *(f32x4*)(out + (rowbase + rg * 4 + j) * DH + cg * 4) = num[j] * dinv;
    }
}

extern "C" void kernel_launch(void* const* d_in, const int* in_sizes, int n_in,
                              void* d_out, int out_size, void* d_ws, size_t ws_size,
                              hipStream_t stream) {
    const f32* q    = (const f32*)d_in[0];
    const f32* k    = (const f32*)d_in[1];
    const f32* v    = (const f32*)d_in[2];
    const f32* proj = (const f32*)d_in[3];
    f32* out     = (f32*)d_out;
    f32* ctx_ws  = (f32*)d_ws;
    f32* ksum_ws = ctx_ws + CTX_FLOATS;

    hipLaunchKernelGGL(zero_ws_kernel, dim3(WS_FLOATS / 4 / 256), dim3(256), 0,
                       stream, (f32x4*)d_ws);
    hipLaunchKernelGGL(kside_kernel, dim3(BH * 16), dim3(256), 0, stream,
                       k, v, proj, ctx_ws, ksum_ws);
    hipLaunchKernelGGL(qside_kernel, dim3(BH * 64), dim3(256), 0, stream,
                       q, proj, ctx_ws, ksum_ws, out);
}

// Round 7
// 770.299 us; speedup vs baseline: 1.5576x; 1.5576x over previous
//
#include <hip/hip_runtime.h>
#include <cstdint>

#define BH    64
#define NSEQ  4096
#define DH    64
#define MF    256
#define EPS   1e-6f

typedef float f32;
typedef __attribute__((ext_vector_type(4))) float f32x4;

// ws layout: [ctx: 64*256*64 f32][ksum: 64*256 f32] — every cell written
// exactly once by kside (no atomics, no zero pass needed).
#define CTX_FLOATS (BH * MF * 64)
#define ZV ((f32x4){0.f, 0.f, 0.f, 0.f})
#define SW(q, r) ((q) ^ ((r) & 15))

// gelu(s) = 0.5*s*(1+erf(s/sqrt2)) + EPS, erf via A&S 7.1.26 (|err|<=1.5e-7)
__device__ __forceinline__ float gelu_eps(float s) {
    float x  = s * 0.70710678118654752f;
    float ax = fabsf(x);
    float t  = __builtin_amdgcn_rcpf(fmaf(0.3275911f, ax, 1.0f));
    float p  = t * fmaf(t, fmaf(t, fmaf(t, fmaf(t, 1.061405429f, -1.453152027f),
                                        1.421413741f), -0.284496736f), 0.254829592f);
    float e  = __expf(-(ax * ax));
    float er = copysignf(fmaf(-p, e, 1.0f), x);
    return fmaf(0.5f * s, er, fmaf(0.5f, s, EPS));
}

// stage P^T chunk f (64 feats x 64 d) transposed+swizzled: sP[d][fq ^ (d&15)]
// (used by qside, verbatim round-0)
__device__ __forceinline__ void stage_P(const f32* __restrict__ Pg_, int f,
                                        f32x4* sP, int tid) {
    const f32x4* Pg = (const f32x4*)(Pg_ + (size_t)f * 64 * DH);
    f32* base = (f32*)sP;
    #pragma unroll
    for (int p = 0; p < 4; ++p) {
        int m2 = tid + p * 256;          // 0..1023
        int feat = m2 >> 4, dq = m2 & 15;
        f32x4 val = Pg[m2];
        #pragma unroll
        for (int jj = 0; jj < 4; ++jj) {
            int d = dq * 4 + jj;
            base[d * 64 + (SW(feat >> 2, d) << 2) + (feat & 3)] = val[jj];
        }
    }
}

// ---------------------------------------------------------------------------
// kside: grid 64bh x 8fg — each block owns feats fg*32..+31 over ALL 4096
// rows => every ctx/ksum cell has exactly ONE writer: plain stores, ZERO
// global atomics (round 0/5/6 counters: 263-471 MB of WRITE_SIZE was
// memory-side atomic RMW traffic; data is only 4.2 MB).
// 16 tiles x 256 rows. kp = gelu(K@P^T)+eps ; ctx += kp^T@V (K-split over
// 4 waves, reduced via LDS at end) ; ksum = colsum(kp).
// ---------------------------------------------------------------------------
__global__ __launch_bounds__(256, 2) void kside_kernel(
    const f32* __restrict__ Kg_, const f32* __restrict__ Vg_,
    const f32* __restrict__ Pg_, f32* __restrict__ ctx_ws,
    f32* __restrict__ ksum_ws)
{
    __shared__ f32x4 sP[64 * 8];     // 8 KB  [d][fq ^ (d&7)]
    __shared__ f32x4 kp[256 * 8];    // 32 KB [row][fq ^ (row&7)]

    const int tid = threadIdx.x;
    // XCD swizzle (proven, FETCH 264->66 MB): slot = fg*64 + bh => slot%8 =
    // bh%8 -> the 8 same-bh blocks (sharing K/V) land on one XCD's L2.
    const int b   = ((blockIdx.x & 63) << 3) | (blockIdx.x >> 6);
    const int fg  = b & 7;
    const int bh  = b >> 3;
    const size_t rowbase = (size_t)bh * NSEQ;

    const int srg = tid >> 3, sfg = tid & 7;    // S: 32 grp x 8 rows, 8 fq
    const int g = tid >> 6, t6 = tid & 63;      // ctx: 4 waves split K
    const int cfg = t6 >> 3, ceg = t6 & 7;      // 8 fq x 8 e-pairs

    // stage P chunk: feats fg*32..+31, layout sP[d][fq ^ (d&7)]
    {
        const f32x4* Pg = (const f32x4*)(Pg_ + (size_t)fg * 32 * DH);
        f32* base = (f32*)sP;
        #pragma unroll
        for (int p = 0; p < 2; ++p) {
            int m2 = tid + p * 256;          // 0..511 quads
            int feat = m2 >> 4, dq = m2 & 15;
            f32x4 val = Pg[m2];
            #pragma unroll
            for (int jj = 0; jj < 4; ++jj) {
                int d = dq * 4 + jj;
                base[d * 32 + (((feat >> 2) ^ (d & 7)) << 2) + (feat & 3)] = val[jj];
            }
        }
    }
    __syncthreads();

    f32x4 ctxacc[4][2];              // 4 feats (quad cfg) x 8 e
    f32x4 ksp = ZV;
    #pragma unroll
    for (int fi = 0; fi < 4; ++fi) { ctxacc[fi][0] = ZV; ctxacc[fi][1] = ZV; }

    for (int t = 0; t < 16; ++t) {
        const f32* Kg = Kg_ + (rowbase + t * 256) * DH;

        // S-GEMM: 8 rows x 4 feats, K=64 (per-thread shape identical to R0)
        f32x4 s[8];
        #pragma unroll
        for (int j = 0; j < 8; ++j) s[j] = ZV;
        #pragma unroll 4
        for (int kb = 0; kb < 16; ++kb) {
            f32x4 a[8];
            #pragma unroll
            for (int j = 0; j < 8; ++j)
                a[j] = *(const f32x4*)(Kg + (size_t)(srg * 8 + j) * DH + kb * 4);
            #pragma unroll
            for (int kk = 0; kk < 4; ++kk) {
                int d = kb * 4 + kk;
                f32x4 bq = sP[d * 8 + (sfg ^ (d & 7))];
                #pragma unroll
                for (int j = 0; j < 8; ++j) s[j] += a[j][kk] * bq;
            }
        }
        f32x4 gq[8];
        #pragma unroll
        for (int j = 0; j < 8; ++j) {
            #pragma unroll
            for (int i = 0; i < 4; ++i) gq[j][i] = gelu_eps(s[j][i]);
            ksp += gq[j];
        }
        __syncthreads();   // prev-tile ctx-GEMM kp reads done
        #pragma unroll
        for (int j = 0; j < 8; ++j) {
            int row = srg * 8 + j;
            kp[row * 8 + (sfg ^ (row & 7))] = gq[j];
        }
        __syncthreads();   // kp ready

        // ctx-GEMM: wave g covers rows g*64..+63; thread 4f x 8e
        const f32* Vg = Vg_ + (rowbase + t * 256 + g * 64) * DH;
        #pragma unroll 4
        for (int k = 0; k < 64; ++k) {
            int row = g * 64 + k;
            f32x4 a0 = kp[row * 8 + (cfg ^ (row & 7))];
            f32x4 b0 = *(const f32x4*)(Vg + (size_t)k * DH + ceg * 8);
            f32x4 b1 = *(const f32x4*)(Vg + (size_t)k * DH + ceg * 8 + 4);
            #pragma unroll
            for (int fi = 0; fi < 4; ++fi) {
                ctxacc[fi][0] += a0[fi] * b0;
                ctxacc[fi][1] += a0[fi] * b1;
            }
        }
    }

    __syncthreads();                 // kp & sP dead
    // ksum partials -> sP scratch: [sfg][srg]
    ((f32x4*)sP)[sfg * 32 + srg] = ksp;

    // ctx: reduce the 4 wave-partials through LDS (kp area, 8 KB used)
    f32* Lc = (f32*)kp;
    #pragma unroll
    for (int gg = 0; gg < 4; ++gg) {
        if (g == gg) {
            #pragma unroll
            for (int fi = 0; fi < 4; ++fi)
                #pragma unroll
                for (int h = 0; h < 2; ++h)
                    #pragma unroll
                    for (int ei = 0; ei < 4; ++ei) {
                        int cell = (cfg * 4 + fi) * 64 + ceg * 8 + h * 4 + ei;
                        float v = ctxacc[fi][h][ei];
                        if (gg == 0) Lc[cell] = v; else Lc[cell] += v;
                    }
        }
        __syncthreads();
    }

    // ksum final: 8 threads sum 32 partials each, plain store (single writer)
    if (tid < 8) {
        f32x4 sum = ZV;
        #pragma unroll
        for (int r = 0; r < 32; ++r) sum += ((f32x4*)sP)[tid * 32 + r];
        *(f32x4*)(ksum_ws + (size_t)bh * MF + fg * 32 + tid * 4) = sum;
    }

    // ctx store: 8 KB coalesced plain stores (single writer block)
    f32x4* Cg = (f32x4*)(ctx_ws + ((size_t)bh * MF + fg * 32) * 64);
    Cg[tid]       = ((f32x4*)Lc)[tid];
    Cg[tid + 256] = ((f32x4*)Lc)[tid + 256];
}

// ---------------------------------------------------------------------------
// qside: verbatim round-0 (435 us, passed). grid 64bh x 32ch, 128 rows.
// qp = gelu(Q@P^T)+eps ; num = qp@ctx ; den = qp.ksum ; out = num/den.
// ---------------------------------------------------------------------------
__global__ __launch_bounds__(256, 2) void qside_kernel(
    const f32* __restrict__ Qg_, const f32* __restrict__ Pg_,
    const f32* __restrict__ ctx_ws, const f32* __restrict__ ksum_ws,
    f32* __restrict__ out)
{
    __shared__ f32x4 qp[128 * 16];   // 32 KB
    __shared__ f32x4 sU[64 * 16];    // 16 KB: P^T then ctx chunk
    __shared__ f32x4 sks[64];        // 1 KB

    const int tid = threadIdx.x;
    const int bh  = blockIdx.x >> 5;
    const int ch  = blockIdx.x & 31;
    const size_t rowbase = (size_t)bh * NSEQ + ch * 128;

    const int rg = tid >> 4, cg = tid & 15;   // S: 8r x 1 fq ; num: 8r x 1 eq

    if (tid < 64) sks[tid] = ((const f32x4*)(ksum_ws + (size_t)bh * MF))[tid];

    const f32* Qg = Qg_ + rowbase * DH;

    f32x4 num[8];
    float den[8];
    #pragma unroll
    for (int j = 0; j < 8; ++j) { num[j] = ZV; den[j] = 0.f; }

    for (int f = 0; f < 4; ++f) {
        stage_P(Pg_, f, sU, tid);
        __syncthreads();   // B1: sP ready (f=0 also covers sks)

        // S-GEMM: 8 rows x 4 feats, K=64
        f32x4 s[8];
        #pragma unroll
        for (int j = 0; j < 8; ++j) s[j] = ZV;
        #pragma unroll 4
        for (int kb = 0; kb < 16; ++kb) {
            f32x4 a[8];
            #pragma unroll
            for (int j = 0; j < 8; ++j)
                a[j] = *(const f32x4*)(Qg + (size_t)(rg * 8 + j) * DH + kb * 4);
            #pragma unroll
            for (int kk = 0; kk < 4; ++kk) {
                int d = kb * 4 + kk;
                f32x4 bq = sU[d * 16 + SW(cg, d)];
                #pragma unroll
                for (int j = 0; j < 8; ++j) s[j] += a[j][kk] * bq;
            }
        }
        #pragma unroll
        for (int j = 0; j < 8; ++j) {
            int row = rg * 8 + j;
            f32x4 gq;
            #pragma unroll
            for (int i = 0; i < 4; ++i) gq[i] = gelu_eps(s[j][i]);
            qp[row * 16 + SW(cg, row)] = gq;
        }
        __syncthreads();   // B2: qp ready AND sU (P) reads done

        {   // stage ctx chunk into sU, swizzled [k][eq ^ (k&15)]
            const f32x4* Cg = (const f32x4*)(ctx_ws + ((size_t)bh * MF + f * 64) * 64);
            #pragma unroll
            for (int p = 0; p < 4; ++p) {
                int m2 = tid + p * 256;
                int k = m2 >> 4, eq = m2 & 15;
                sU[k * 16 + SW(eq, k)] = Cg[m2];
            }
        }
        __syncthreads();   // B3: sctx ready

        // num-GEMM: 8 rows x 4 e, K=64 ; den folded in
        #pragma unroll 4
        for (int kb = 0; kb < 16; ++kb) {
            f32x4 a[8];
            #pragma unroll
            for (int j = 0; j < 8; ++j) {
                int row = rg * 8 + j;
                a[j] = qp[row * 16 + SW(kb, row)];
            }
            f32x4 ks = sks[f * 16 + kb];
            #pragma unroll
            for (int kk = 0; kk < 4; ++kk) {
                int k = kb * 4 + kk;
                f32x4 bq = sU[k * 16 + SW(cg, k)];
                #pragma unroll
                for (int j = 0; j < 8; ++j) num[j] += a[j][kk] * bq;
            }
            #pragma unroll
            for (int j = 0; j < 8; ++j)
                den[j] += a[j][0] * ks[0] + a[j][1] * ks[1]
                        + a[j][2] * ks[2] + a[j][3] * ks[3];
        }
        __syncthreads();   // B4: sU/qp reads done before next-f staging
    }

    #pragma unroll
    for (int j = 0; j < 8; ++j) {
        float dinv = 1.0f / den[j];
        *(f32x4*)(out + (rowbase + rg * 8 + j) * DH + cg * 4) = num[j] * dinv;
    }
}

extern "C" void kernel_launch(void* const* d_in, const int* in_sizes, int n_in,
                              void* d_out, int out_size, void* d_ws, size_t ws_size,
                              hipStream_t stream) {
    const f32* q    = (const f32*)d_in[0];
    const f32* k    = (const f32*)d_in[1];
    const f32* v    = (const f32*)d_in[2];
    const f32* proj = (const f32*)d_in[3];
    f32* out     = (f32*)d_out;
    f32* ctx_ws  = (f32*)d_ws;
    f32* ksum_ws = ctx_ws + CTX_FLOATS;

    // no zero pass: kside writes every ctx/ksum cell exactly once
    hipLaunchKernelGGL(kside_kernel, dim3(BH * 8), dim3(256), 0, stream,
                       k, v, proj, ctx_ws, ksum_ws);
    hipLaunchKernelGGL(qside_kernel, dim3(BH * 32), dim3(256), 0, stream,
                       q, proj, ctx_ws, ksum_ws, out);
}